// Round 8
// baseline (130.404 us; speedup 1.0000x reference)
//
#include <hip/hip_runtime.h>

// ImplicitNetOC: u = clip(-pB) ; pB = relu(relu([x,t]W1+b1)W2+b2) @ (W3@Bmat) + b3@Bmat
// R20: 4 waves/SIMD via ONE 1024-thread block (16 waves), BM=128.
// Diagnosis chain: R16~R17~R19 all ~42-45us with MfmaUtil 18 / VALUBusy 21 /
// HBM 7% / Occupancy 18% -> TLP-starved latency-bound at 2 waves/SIMD.
// R19's 2-blocks/CU failed because 116 arch + 32 agpr = 148 regs/wave allows
// only 3 waves/SIMD (pool 512), and 512-thr blocks need 4 -> block atomicity
// kept 1 block/CU. Fix: a single 16-wave block MUST fit 128 regs/wave total
// (16x128 = pool), forcing the allocator to the right budget; feasible only
// at acc[2][4]=32 AGPR (wave tile M=32xN=64, 8mg x 2ng) + ~96 arch.
// L2 kt-loop unroll(2) bounds A-frag liveness. LDS 144 KB, swizzle unchanged,
// per-CU work totals unchanged; barrier drains halve vs R19 (16 vs 32/CU).
// Readout: WRITE ~8-9MB & VGPR<=~96 & Occ 35-45% = win (~110us);
// WRITE>=50MB = spilled -> revert R16.

typedef __bf16 bf16;
typedef __bf16 bf16x8 __attribute__((ext_vector_type(8)));
typedef __bf16 bf16x4 __attribute__((ext_vector_type(4)));
typedef float  f32x4  __attribute__((ext_vector_type(4)));

#define HID    256
#define SDIM   64
#define CDIM   16
#define BM     128
#define GRID   256      // 1024 tiles / ITERS
#define ITERS  4
// sH row: 256 bf16 (512 B); sX row: 64 bf16 (128 B); 16B granules XOR-swizzled.

// ws byte offsets (pack format unchanged from R8)
#define OFF_W2P 0        // 8192 entries x 16 B (8kt x 16nt x 64lane)
#define OFF_W3P 131072   // 512 entries x 16 B (8kt x 64lane)
#define OFF_W1P 139264   // 2048 entries x 16 B (2kt x 16nt x 64lane)
#define OFF_B1E 172032   // 256 f32
#define OFF_B3B 173056   // 16 f32

#define MFMA(a, b, c) __builtin_amdgcn_mfma_f32_16x16x32_bf16(a, b, c, 0, 0, 0)

// swizzled sH index: element (row=batch 0..127, h=hidden 0..255). granule=16B.
__device__ __forceinline__ int sh_idx(int row, int h) {
  return (row << 8) + ((((h >> 3) ^ row) & 7) << 3) + (h & 7) + ((h >> 6) << 6);
}
__device__ __forceinline__ int sx_idx(int row, int k) {
  return (row << 6) + ((((k >> 3) ^ row) & 7) << 3) + (k & 7);
}

// ---- pack kernel: W2/W1/W3B A-frags + folded biases -> ws. 22 x 512 ----
__global__ __launch_bounds__(512)
void oc_pack(const float* __restrict__ t,  const float* __restrict__ W1,
             const float* __restrict__ b1, const float* __restrict__ W2,
             const float* __restrict__ W3, const float* __restrict__ b3,
             const float* __restrict__ Bmat, char* __restrict__ ws) {
  const int gid = blockIdx.x * 512 + threadIdx.x;
  if (gid < 8192) {
    const int lane = gid & 63, tt = gid >> 6;
    const int nt = tt & 15, kt = tt >> 4;
    const int m = nt * 16 + (lane & 15);
    const int k0 = kt * 32 + ((lane >> 4) << 3);
    bf16x8 v;
#pragma unroll
    for (int j = 0; j < 8; ++j) v[j] = (bf16)W2[(k0 + j) * HID + m];
    *(bf16x8*)((bf16*)(ws + OFF_W2P) + (size_t)gid * 8) = v;
  } else if (gid < 8704) {
    const int e = gid - 8192, kt = e >> 6, fl = e & 63;
    const int r0 = kt * 32 + ((fl >> 4) << 3);
    const int c  = fl & 15;
    float aw[8];
#pragma unroll
    for (int j = 0; j < 8; ++j) aw[j] = 0.f;
    for (int m = 0; m < SDIM; ++m) {
      const float bm = Bmat[m * CDIM + c];
#pragma unroll
      for (int j = 0; j < 8; ++j) aw[j] = fmaf(W3[(r0 + j) * SDIM + m], bm, aw[j]);
    }
    bf16x8 v;
#pragma unroll
    for (int j = 0; j < 8; ++j) v[j] = (bf16)aw[j];
    *(bf16x8*)((bf16*)(ws + OFF_W3P) + (size_t)e * 8) = v;
  } else if (gid < 10752) {
    const int e = gid - 8704;
    const int lane = e & 63, tt = e >> 6;
    const int nt = tt & 15, kt = tt >> 4;
    const int m = nt * 16 + (lane & 15);
    const int k0 = kt * 32 + ((lane >> 4) << 3);
    bf16x8 v;
#pragma unroll
    for (int j = 0; j < 8; ++j) v[j] = (bf16)W1[(k0 + j) * HID + m];
    *(bf16x8*)((bf16*)(ws + OFF_W1P) + (size_t)e * 8) = v;
  } else if (gid < 11008) {
    const int h = gid - 10752;
    ((float*)(ws + OFF_B1E))[h] = b1[h] + t[0] * W1[SDIM * HID + h];  // fold t-col
  } else if (gid < 11024) {
    const int c = gid - 11008;
    float s = 0.f;
    for (int m = 0; m < SDIM; ++m) s = fmaf(b3[m], Bmat[m * CDIM + c], s);
    ((float*)(ws + OFF_B3B))[c] = s;
  }
}

// ---- main: 256 blocks x 1024 threads (16 waves), 144 KB LDS, 1 block/CU ----
__global__ __launch_bounds__(1024)
void oc_main(const float* __restrict__ x, const float* __restrict__ b2,
             const char* __restrict__ ws, float* __restrict__ out) {
  __shared__ bf16 sH1[BM * 256];   // 64 KB: H1 swizzled; reused as H2-lo
  __shared__ bf16 sH2[BM * 256];   // 64 KB: H2-hi
  __shared__ bf16 sX [BM * 64];    // 16 KB: staged X swizzled
  const int tid  = threadIdx.x;
  const int wave = tid >> 6, lane = tid & 63;
  const int q    = lane >> 4, l = lane & 15;
  const int mg   = wave >> 1;      // m-group 0..7: hidden [32*mg, 32*mg+32)
  const int ng   = wave & 1;       // n-group 0..1: batch rows [64*ng, 64*ng+64)

  const bf16* W2p = (const bf16*)(ws + OFF_W2P);
  const bf16* W3p = (const bf16*)(ws + OFF_W3P);
  const bf16* W1p = (const bf16*)(ws + OFF_W1P);

  // ---- initial X stage: 2048 float4, 2 per thread ----
  {
    const float* xp = x + (size_t)blockIdx.x * BM * SDIM;
#pragma unroll
    for (int i = 0; i < 2; ++i) {
      const int e = i * 1024 + tid;          // 2048 float4 = 128 x 64 floats
      const int r = e >> 4, k4 = (e & 15) * 4;
      const float4 v = *(const float4*)(xp + r * SDIM + k4);
      bf16x4 w = {(bf16)v.x, (bf16)v.y, (bf16)v.z, (bf16)v.w};
      *(bf16x4*)(&sX[sx_idx(r, k4)]) = w;
    }
  }
  __syncthreads();   // sX staged

  f32x4 acc[2][4];   // [mt][nt] : wave tile M=32 hidden x N=64 batch

  for (int it = 0; it < ITERS; ++it) {
    const int tile = blockIdx.x + it * GRID;

    // ---- layer 1: H1 = relu(W1^T X^T + b1); M=32 hidden/wave, N=64 batch ----
#pragma unroll
    for (int mt = 0; mt < 2; ++mt) {
      const float4 v1 = *(const float4*)((const float*)(ws + OFF_B1E) + 32 * mg + 16 * mt + 4 * q);
      const f32x4 bv = {v1.x, v1.y, v1.z, v1.w};
#pragma unroll
      for (int nt = 0; nt < 4; ++nt) acc[mt][nt] = bv;
    }
#pragma unroll
    for (int kt = 0; kt < 2; ++kt) {
      const bf16x8 w1a = *(const bf16x8*)(W1p + ((size_t)(kt * 16 + 2 * mg    ) * 64 + lane) * 8);
      const bf16x8 w1b = *(const bf16x8*)(W1p + ((size_t)(kt * 16 + 2 * mg + 1) * 64 + lane) * 8);
#pragma unroll
      for (int nt = 0; nt < 4; ++nt) {
        const bf16x8 b = *(const bf16x8*)(&sX[sx_idx(64 * ng + 16 * nt + l, 32 * kt + 8 * q)]);
        acc[0][nt] = MFMA(w1a, b, acc[0][nt]);
        acc[1][nt] = MFMA(w1b, b, acc[1][nt]);
      }
    }
#pragma unroll
    for (int mt = 0; mt < 2; ++mt) {
      const int h0 = 32 * mg + 16 * mt + 4 * q;
#pragma unroll
      for (int nt = 0; nt < 4; ++nt) {
        bf16x4 v;
#pragma unroll
        for (int r = 0; r < 4; ++r) v[r] = (bf16)fmaxf(acc[mt][nt][r], 0.f);
        *(bf16x4*)(&sH1[sh_idx(64 * ng + 16 * nt + l, h0)]) = v;
      }
    }
    __syncthreads();   // A: H1 visible; sX reads done

    // ---- layer 2: H2 = relu(W2^T H1 + b2)  K=256 ----
#pragma unroll
    for (int mt = 0; mt < 2; ++mt) {
      const float4 v2 = *(const float4*)(b2 + 32 * mg + 16 * mt + 4 * q);
      const f32x4 bv = {v2.x, v2.y, v2.z, v2.w};
#pragma unroll
      for (int nt = 0; nt < 4; ++nt) acc[mt][nt] = bv;
    }
#pragma unroll 2
    for (int kt = 0; kt < 8; ++kt) {
      const bf16x8 w2a = *(const bf16x8*)(W2p + ((size_t)(kt * 16 + 2 * mg    ) * 64 + lane) * 8);
      const bf16x8 w2b = *(const bf16x8*)(W2p + ((size_t)(kt * 16 + 2 * mg + 1) * 64 + lane) * 8);
#pragma unroll
      for (int nt = 0; nt < 4; ++nt) {
        const bf16x8 b = *(const bf16x8*)(&sH1[sh_idx(64 * ng + 16 * nt + l, 32 * kt + 8 * q)]);
        acc[0][nt] = MFMA(w2a, b, acc[0][nt]);
        acc[1][nt] = MFMA(w2b, b, acc[1][nt]);
      }
    }
    __syncthreads();   // B: sH1 reads done -> overwritable as H2-lo

    // ---- H2 writeback: hi (sH2) + lo residual (sH1), b64 each ----
#pragma unroll
    for (int mt = 0; mt < 2; ++mt) {
      const int h0 = 32 * mg + 16 * mt + 4 * q;
#pragma unroll
      for (int nt = 0; nt < 4; ++nt) {
        bf16x4 hi, lo;
#pragma unroll
        for (int r = 0; r < 4; ++r) {
          const float v = fmaxf(acc[mt][nt][r], 0.f);
          const bf16 h = (bf16)v;
          hi[r] = h;
          lo[r] = (bf16)(v - (float)h);
        }
        const int idx = sh_idx(64 * ng + 16 * nt + l, h0);
        *(bf16x4*)(&sH2[idx]) = hi;
        *(bf16x4*)(&sH1[idx]) = lo;
      }
    }
    __syncthreads();   // C: H2 hi/lo visible

    if (wave < 8) {
      // ---- layer 3 (waves 0-7): 16 rows/wave, row = 16*wave + l ----
      const float4 v3 = *(const float4*)((const float*)(ws + OFF_B3B) + 4 * q);
      f32x4 a3 = {v3.x, v3.y, v3.z, v3.w};
      const int row = 16 * wave + l;
#pragma unroll 2
      for (int kt = 0; kt < 8; ++kt) {
        const bf16x8 w3 = *(const bf16x8*)(W3p + ((size_t)kt * 64 + lane) * 8);
        const int idx = sh_idx(row, 32 * kt + 8 * q);
        const bf16x8 bh = *(const bf16x8*)(&sH2[idx]);
        const bf16x8 bl = *(const bf16x8*)(&sH1[idx]);
        a3 = MFMA(w3, bh, a3);
        a3 = MFMA(w3, bl, a3);
      }
      f32x4 o;
#pragma unroll
      for (int r = 0; r < 4; ++r)
        o[r] = fminf(fmaxf(-a3[r], -1.f), 1.f);
      *(float4*)(&out[((size_t)tile * BM + row) * CDIM + 4 * q]) = *(float4*)&o;
    } else if (it + 1 < ITERS) {
      // ---- waves 8-15: stage next X tile concurrently with layer 3 ----
      const float* xp = x + (size_t)(tile + GRID) * BM * SDIM;
      const int tid2 = tid - 512;            // 0..511
#pragma unroll
      for (int i = 0; i < 4; ++i) {
        const int e = i * 512 + tid2;        // 2048 float4 = 128 x 64 floats
        const int r = e >> 4, k4 = (e & 15) * 4;
        const float4 v = *(const float4*)(xp + r * SDIM + k4);
        bf16x4 w = {(bf16)v.x, (bf16)v.y, (bf16)v.z, (bf16)v.w};
        *(bf16x4*)(&sX[sx_idx(r, k4)]) = w;
      }
    }
    __syncthreads();   // D: L3 reads + stage done before next L1 overwrites sH1/reads sX
  }
}

extern "C" void kernel_launch(void* const* d_in, const int* in_sizes, int n_in,
                              void* d_out, int out_size, void* d_ws, size_t ws_size,
                              hipStream_t stream) {
  const float* x    = (const float*)d_in[0];
  const float* t    = (const float*)d_in[1];
  const float* W1   = (const float*)d_in[2];
  const float* b1   = (const float*)d_in[3];
  const float* W2   = (const float*)d_in[4];
  const float* b2   = (const float*)d_in[5];
  const float* W3   = (const float*)d_in[6];
  const float* b3   = (const float*)d_in[7];
  const float* Bmat = (const float*)d_in[8];
  float* out = (float*)d_out;
  char*  ws  = (char*)d_ws;

  hipLaunchKernelGGL(oc_pack, dim3(22), dim3(512), 0, stream,
                     t, W1, b1, W2, W3, b3, Bmat, ws);
  hipLaunchKernelGGL(oc_main, dim3(GRID), dim3(1024), 0, stream,
                     x, b2, ws, out);
}

// Round 10
// 121.961 us; speedup vs baseline: 1.0692x; 1.0692x over previous
//
#include <hip/hip_runtime.h>

// ImplicitNetOC: u = clip(-pB) ; pB = relu(relu([x,t]W1+b1)W2+b2) @ (W3@Bmat) + b3@Bmat
// R22 = R21 resubmitted verbatim (round-9 bench was an infra failure: container
// failed twice, no counters). R21 = exact revert to R16, measured 123.1 us.
// Session conclusions (R13-R20 evidence):
//  - Structure: 512 thr / 8 waves, BM=128, GRID=256/ITERS=4, acc[2][8] wave
//    tiles (M=32 x N=128), 2 A-frags/kt, full unroll, 144 KB LDS, XOR granule
//    swizzle. oc_main ~39-40 us. All variants tried land 44-45 us or spill:
//    * acc[4][4] retile (R14/R15/R18): >128 live regs -> ~84 MB spill WRITE.
//      The arch-VGPR budget is 128 for this family REGARDLESS of
//      __launch_bounds__ arg2 (R15 vs R18 identical); R17's unroll-1 fix
//      avoided spill but serialized loads (45.3 us, latency-bound).
//    * BM=64 2-blocks/CU (R19): blocked by regs (148/wave allows 3 waves/SIMD,
//      block needs 4) -> still 1 block/CU, 45.0 us.
//    * 1024-thr 16-wave (R20): Occupancy 17.8->37.8% yet STILL 45.0 us ->
//      NOT TLP-starved. Phase floors are shared-resource (LDS pipe ~4.1K
//      cyc/tile in L2 phase + conflicts) + barrier lockstep; extra waves queue.
//  - dur_us ~= 84 us harness ws-poison fills (268 MB @ 75% HBM peak, its own
//    roofline, untouchable) + ~1.5 us pack + oc_main.
//  - Remaining oc_main headroom (~20 us over the LDS floor) is intra-phase
//    dependency serialization; would need T3-style split-phase/counted-vmcnt
//    restructuring -- do NOT attempt without disasm (4 regressions this
//    session came from blind structural edits). Next session: -save-temps
//    mnemonic histogram of the L2 phase first.

typedef __bf16 bf16;
typedef __bf16 bf16x8 __attribute__((ext_vector_type(8)));
typedef __bf16 bf16x4 __attribute__((ext_vector_type(4)));
typedef float  f32x4  __attribute__((ext_vector_type(4)));

#define HID    256
#define SDIM   64
#define CDIM   16
#define BM     128
#define GRID   256      // 1024 tiles / ITERS
#define ITERS  4
// sH row: 256 bf16 (512 B); sX row: 64 bf16 (128 B); 16B granules XOR-swizzled.

// ws byte offsets (pack format unchanged from R8)
#define OFF_W2P 0        // 8192 entries x 16 B (8kt x 16nt x 64lane)
#define OFF_W3P 131072   // 512 entries x 16 B (8kt x 64lane)
#define OFF_W1P 139264   // 2048 entries x 16 B (2kt x 16nt x 64lane)
#define OFF_B1E 172032   // 256 f32
#define OFF_B3B 173056   // 16 f32

#define MFMA(a, b, c) __builtin_amdgcn_mfma_f32_16x16x32_bf16(a, b, c, 0, 0, 0)

// swizzled sH index: element (row=batch, h=hidden). granule = 8 bf16 = 16 B.
__device__ __forceinline__ int sh_idx(int row, int h) {
  return (row << 8) + ((((h >> 3) ^ row) & 7) << 3) + (h & 7) + ((h >> 6) << 6);
}
// h < 256, granules/row = 32; swizzle only the low 3 granule bits:
// idx = row*256 + (g & ~7)*8 + ((g&7)^(row&7))*8 + (h&7), g = h>>3.

__device__ __forceinline__ int sx_idx(int row, int k) {
  return (row << 6) + ((((k >> 3) ^ row) & 7) << 3) + (k & 7);
}

// ---- pack kernel: W2/W1/W3B A-frags + folded biases -> ws. 22 x 512 ----
__global__ __launch_bounds__(512)
void oc_pack(const float* __restrict__ t,  const float* __restrict__ W1,
             const float* __restrict__ b1, const float* __restrict__ W2,
             const float* __restrict__ W3, const float* __restrict__ b3,
             const float* __restrict__ Bmat, char* __restrict__ ws) {
  const int gid = blockIdx.x * 512 + threadIdx.x;
  if (gid < 8192) {
    const int lane = gid & 63, tt = gid >> 6;
    const int nt = tt & 15, kt = tt >> 4;
    const int m = nt * 16 + (lane & 15);
    const int k0 = kt * 32 + ((lane >> 4) << 3);
    bf16x8 v;
#pragma unroll
    for (int j = 0; j < 8; ++j) v[j] = (bf16)W2[(k0 + j) * HID + m];
    *(bf16x8*)((bf16*)(ws + OFF_W2P) + (size_t)gid * 8) = v;
  } else if (gid < 8704) {
    const int e = gid - 8192, kt = e >> 6, fl = e & 63;
    const int r0 = kt * 32 + ((fl >> 4) << 3);
    const int c  = fl & 15;
    float aw[8];
#pragma unroll
    for (int j = 0; j < 8; ++j) aw[j] = 0.f;
    for (int m = 0; m < SDIM; ++m) {
      const float bm = Bmat[m * CDIM + c];
#pragma unroll
      for (int j = 0; j < 8; ++j) aw[j] = fmaf(W3[(r0 + j) * SDIM + m], bm, aw[j]);
    }
    bf16x8 v;
#pragma unroll
    for (int j = 0; j < 8; ++j) v[j] = (bf16)aw[j];
    *(bf16x8*)((bf16*)(ws + OFF_W3P) + (size_t)e * 8) = v;
  } else if (gid < 10752) {
    const int e = gid - 8704;
    const int lane = e & 63, tt = e >> 6;
    const int nt = tt & 15, kt = tt >> 4;
    const int m = nt * 16 + (lane & 15);
    const int k0 = kt * 32 + ((lane >> 4) << 3);
    bf16x8 v;
#pragma unroll
    for (int j = 0; j < 8; ++j) v[j] = (bf16)W1[(k0 + j) * HID + m];
    *(bf16x8*)((bf16*)(ws + OFF_W1P) + (size_t)e * 8) = v;
  } else if (gid < 11008) {
    const int h = gid - 10752;
    ((float*)(ws + OFF_B1E))[h] = b1[h] + t[0] * W1[SDIM * HID + h];  // fold t-col
  } else if (gid < 11024) {
    const int c = gid - 11008;
    float s = 0.f;
    for (int m = 0; m < SDIM; ++m) s = fmaf(b3[m], Bmat[m * CDIM + c], s);
    ((float*)(ws + OFF_B3B))[c] = s;
  }
}

// ---- main: 256 blocks x 512 threads (8 waves), 144 KB LDS, 1 block/CU ----
__global__ __launch_bounds__(512, 2)
void oc_main(const float* __restrict__ x, const float* __restrict__ b2,
             const char* __restrict__ ws, float* __restrict__ out) {
  __shared__ bf16 sH1[BM * 256];   // H1 [batch][hidden] swizzled; reused as H2-lo
  __shared__ bf16 sH2[BM * 256];   // H2-hi
  __shared__ bf16 sX [BM * 64];    // staged X [batch][k] swizzled
  const int tid  = threadIdx.x;
  const int wave = tid >> 6, lane = tid & 63;
  const int q    = lane >> 4, l = lane & 15;

  const bf16* W2p = (const bf16*)(ws + OFF_W2P);
  const bf16* W3p = (const bf16*)(ws + OFF_W3P);
  const bf16* W1p = (const bf16*)(ws + OFF_W1P);

  // ---- initial X stage: 2048 float4, 4 per thread ----
  {
    const float* xp = x + (size_t)blockIdx.x * BM * SDIM;
#pragma unroll
    for (int i = 0; i < 4; ++i) {
      const int e = i * 512 + tid;           // 2048 float4 = 128 x 64 floats
      const int r = e >> 4, k4 = (e & 15) * 4;
      const float4 v = *(const float4*)(xp + r * SDIM + k4);
      bf16x4 w = {(bf16)v.x, (bf16)v.y, (bf16)v.z, (bf16)v.w};
      *(bf16x4*)(&sX[sx_idx(r, k4)]) = w;
    }
  }

  // ---- biases: wave owns 32 hidden (mt 0..1), h0 = 32*wave + 16*mt + 4*q ----
  f32x4 b1e[2], b2e[2];
#pragma unroll
  for (int mt = 0; mt < 2; ++mt) {
    const int h0 = 32 * wave + 16 * mt + 4 * q;
    const float4 v1 = *(const float4*)((const float*)(ws + OFF_B1E) + h0);
    const float4 v2 = *(const float4*)(b2 + h0);
    b1e[mt] = (f32x4){v1.x, v1.y, v1.z, v1.w};
    b2e[mt] = (f32x4){v2.x, v2.y, v2.z, v2.w};
  }
  f32x4 b3t;
  {
    const float4 v = *(const float4*)((const float*)(ws + OFF_B3B) + 4 * q);
    b3t = (f32x4){v.x, v.y, v.z, v.w};
  }
  __syncthreads();   // sX staged

  f32x4 acc[2][8];   // [mt][nt]

  for (int it = 0; it < ITERS; ++it) {
    const int tile = blockIdx.x + it * GRID;

    // ---- layer 1: H1 = relu(W1^T X^T + b1); M=32 hidden/wave, N=128 batch ----
#pragma unroll
    for (int mt = 0; mt < 2; ++mt)
#pragma unroll
      for (int nt = 0; nt < 8; ++nt) acc[mt][nt] = b1e[mt];
#pragma unroll
    for (int kt = 0; kt < 2; ++kt) {
      const bf16x8 w1a = *(const bf16x8*)(W1p + ((size_t)(kt * 16 + 2 * wave    ) * 64 + lane) * 8);
      const bf16x8 w1b = *(const bf16x8*)(W1p + ((size_t)(kt * 16 + 2 * wave + 1) * 64 + lane) * 8);
#pragma unroll
      for (int nt = 0; nt < 8; ++nt) {
        const bf16x8 b = *(const bf16x8*)(&sX[sx_idx(16 * nt + l, 32 * kt + 8 * q)]);
        acc[0][nt] = MFMA(w1a, b, acc[0][nt]);
        acc[1][nt] = MFMA(w1b, b, acc[1][nt]);
      }
    }
#pragma unroll
    for (int mt = 0; mt < 2; ++mt) {
      const int h0 = 32 * wave + 16 * mt + 4 * q;
#pragma unroll
      for (int nt = 0; nt < 8; ++nt) {
        bf16x4 v;
#pragma unroll
        for (int r = 0; r < 4; ++r) v[r] = (bf16)fmaxf(acc[mt][nt][r], 0.f);
        *(bf16x4*)(&sH1[sh_idx(16 * nt + l, h0)]) = v;
      }
    }
    __syncthreads();   // A: H1 visible; sX reads done

    // ---- layer 2: H2 = relu(W2^T H1 + b2)  K=256; W2 frags streamed from ws ----
#pragma unroll
    for (int mt = 0; mt < 2; ++mt)
#pragma unroll
      for (int nt = 0; nt < 8; ++nt) acc[mt][nt] = b2e[mt];
#pragma unroll
    for (int kt = 0; kt < 8; ++kt) {
      const bf16x8 w2a = *(const bf16x8*)(W2p + ((size_t)(kt * 16 + 2 * wave    ) * 64 + lane) * 8);
      const bf16x8 w2b = *(const bf16x8*)(W2p + ((size_t)(kt * 16 + 2 * wave + 1) * 64 + lane) * 8);
#pragma unroll
      for (int nt = 0; nt < 8; ++nt) {
        const bf16x8 b = *(const bf16x8*)(&sH1[sh_idx(16 * nt + l, 32 * kt + 8 * q)]);
        acc[0][nt] = MFMA(w2a, b, acc[0][nt]);
        acc[1][nt] = MFMA(w2b, b, acc[1][nt]);
      }
    }
    __syncthreads();   // B: sH1 reads done -> overwritable as H2-lo

    // ---- H2 writeback: hi (sH2) + lo residual (sH1), b64 each ----
#pragma unroll
    for (int mt = 0; mt < 2; ++mt) {
      const int h0 = 32 * wave + 16 * mt + 4 * q;
#pragma unroll
      for (int nt = 0; nt < 8; ++nt) {
        bf16x4 hi, lo;
#pragma unroll
        for (int r = 0; r < 4; ++r) {
          const float v = fmaxf(acc[mt][nt][r], 0.f);
          const bf16 h = (bf16)v;
          hi[r] = h;
          lo[r] = (bf16)(v - (float)h);
        }
        const int idx = sh_idx(16 * nt + l, h0);
        *(bf16x4*)(&sH2[idx]) = hi;
        *(bf16x4*)(&sH1[idx]) = lo;
      }
    }
    __syncthreads();   // C: H2 hi/lo visible

    if (wave < 4) {
      // ---- layer 3 (waves 0-3): 32 rows/wave, two 16-row groups ----
#pragma unroll
      for (int g = 0; g < 2; ++g) {
        const int row = 32 * wave + 16 * g + l;
        f32x4 a3 = b3t;
#pragma unroll
        for (int kt = 0; kt < 8; ++kt) {
          const bf16x8 w3 = *(const bf16x8*)(W3p + ((size_t)kt * 64 + lane) * 8);
          const int idx = sh_idx(row, 32 * kt + 8 * q);
          const bf16x8 bh = *(const bf16x8*)(&sH2[idx]);
          const bf16x8 bl = *(const bf16x8*)(&sH1[idx]);
          a3 = MFMA(w3, bh, a3);
          a3 = MFMA(w3, bl, a3);
        }
        f32x4 o;
#pragma unroll
        for (int r = 0; r < 4; ++r)
          o[r] = fminf(fmaxf(-a3[r], -1.f), 1.f);
        *(float4*)(&out[((size_t)tile * BM + row) * CDIM + 4 * q]) = *(float4*)&o;
      }
    } else if (it + 1 < ITERS) {
      // ---- waves 4-7: stage next X tile concurrently with layer 3 ----
      const float* xp = x + (size_t)(tile + GRID) * BM * SDIM;
      const int tid2 = tid - 256;            // 0..255
#pragma unroll
      for (int i = 0; i < 8; ++i) {
        const int e = i * 256 + tid2;        // 2048 float4 = 128 x 64 floats
        const int r = e >> 4, k4 = (e & 15) * 4;
        const float4 v = *(const float4*)(xp + r * SDIM + k4);
        bf16x4 w = {(bf16)v.x, (bf16)v.y, (bf16)v.z, (bf16)v.w};
        *(bf16x4*)(&sX[sx_idx(r, k4)]) = w;
      }
    }
    __syncthreads();   // D: L3 reads + stage done before next L1 overwrites sH1/reads sX
  }
}

extern "C" void kernel_launch(void* const* d_in, const int* in_sizes, int n_in,
                              void* d_out, int out_size, void* d_ws, size_t ws_size,
                              hipStream_t stream) {
  const float* x    = (const float*)d_in[0];
  const float* t    = (const float*)d_in[1];
  const float* W1   = (const float*)d_in[2];
  const float* b1   = (const float*)d_in[3];
  const float* W2   = (const float*)d_in[4];
  const float* b2   = (const float*)d_in[5];
  const float* W3   = (const float*)d_in[6];
  const float* b3   = (const float*)d_in[7];
  const float* Bmat = (const float*)d_in[8];
  float* out = (float*)d_out;
  char*  ws  = (char*)d_ws;

  hipLaunchKernelGGL(oc_pack, dim3(22), dim3(512), 0, stream,
                     t, W1, b1, W2, W3, b3, Bmat, ws);
  hipLaunchKernelGGL(oc_main, dim3(GRID), dim3(512), 0, stream,
                     x, b2, ws, out);
}

// Round 11
// 118.761 us; speedup vs baseline: 1.0980x; 1.0269x over previous
//
#include <hip/hip_runtime.h>

// ImplicitNetOC: u = clip(-pB) ; pB = relu(relu([x,t]W1+b1)W2+b2) @ (W3@Bmat) + b3@Bmat
// R23 = R16/R22 structure (best measured: 122.0 us) with the datapath switched
// bf16 -> fp16 and the H2 lo-residual ELIMINATED:
//  - Rationale: absmax was bit-identical 2^-6 across ALL rounds => error is
//    dtype quantization (bf16 2^-8 on X/H1/W), not scheduling. fp16 (2^-11) is
//    8x more precise per element with zero overflow risk here (|X|<6,
//    |H1|,|H2|~O(1), |W|<0.2), so single-fp16 H2 beats the old bf16 error
//    floor -> the hi/lo trick (which existed only for bf16's short mantissa)
//    is dead weight: 2x L3 MFMAs, 2x L3 reads, 2x writeback stores, and
//    barrier B (which only protected the sH1-as-H2lo overwrite).
//  - New schedule: 3 barriers/tile (A: sH1 ready; C: sH2 ready; D: L3 reads +
//    sX stage done). Verified: sH1 written P0 / read P1; sH2 written P1 /
//    read P2; sX written P2 / read next P0 -- all separated by A/C/D.
//  - mfma_f32_16x16x32_f16: same shape/rate as bf16 (1955 vs 2075 TF ubench).
// Everything else identical to R22: 512 thr / 8 waves, BM=128, GRID=256,
// ITERS=4, acc[2][8], 144 KB LDS, XOR granule swizzle, same pack layout.
// Readout: absmax ~0.002-0.008 (improves) & dur ~116-119 = win; absmax
// worse or fail = dtype theory wrong, revert to R22.

typedef _Float16 f16;
typedef _Float16 f16x8 __attribute__((ext_vector_type(8)));
typedef _Float16 f16x4 __attribute__((ext_vector_type(4)));
typedef float    f32x4 __attribute__((ext_vector_type(4)));

#define HID    256
#define SDIM   64
#define CDIM   16
#define BM     128
#define GRID   256      // 1024 tiles / ITERS
#define ITERS  4
// sH row: 256 f16 (512 B); sX row: 64 f16 (128 B); 16B granules XOR-swizzled.

// ws byte offsets (pack format unchanged from R8, dtype now fp16)
#define OFF_W2P 0        // 8192 entries x 16 B (8kt x 16nt x 64lane)
#define OFF_W3P 131072   // 512 entries x 16 B (8kt x 64lane)
#define OFF_W1P 139264   // 2048 entries x 16 B (2kt x 16nt x 64lane)
#define OFF_B1E 172032   // 256 f32
#define OFF_B3B 173056   // 16 f32

#define MFMA(a, b, c) __builtin_amdgcn_mfma_f32_16x16x32_f16(a, b, c, 0, 0, 0)

// swizzled sH index: element (row=batch, h=hidden). granule = 8 f16 = 16 B.
__device__ __forceinline__ int sh_idx(int row, int h) {
  return (row << 8) + ((((h >> 3) ^ row) & 7) << 3) + (h & 7) + ((h >> 6) << 6);
}
// h < 256, granules/row = 32; swizzle only the low 3 granule bits:
// idx = row*256 + (g & ~7)*8 + ((g&7)^(row&7))*8 + (h&7), g = h>>3.

__device__ __forceinline__ int sx_idx(int row, int k) {
  return (row << 6) + ((((k >> 3) ^ row) & 7) << 3) + (k & 7);
}

// ---- pack kernel: W2/W1/W3B A-frags + folded biases -> ws. 22 x 512 ----
__global__ __launch_bounds__(512)
void oc_pack(const float* __restrict__ t,  const float* __restrict__ W1,
             const float* __restrict__ b1, const float* __restrict__ W2,
             const float* __restrict__ W3, const float* __restrict__ b3,
             const float* __restrict__ Bmat, char* __restrict__ ws) {
  const int gid = blockIdx.x * 512 + threadIdx.x;
  if (gid < 8192) {
    const int lane = gid & 63, tt = gid >> 6;
    const int nt = tt & 15, kt = tt >> 4;
    const int m = nt * 16 + (lane & 15);
    const int k0 = kt * 32 + ((lane >> 4) << 3);
    f16x8 v;
#pragma unroll
    for (int j = 0; j < 8; ++j) v[j] = (f16)W2[(k0 + j) * HID + m];
    *(f16x8*)((f16*)(ws + OFF_W2P) + (size_t)gid * 8) = v;
  } else if (gid < 8704) {
    const int e = gid - 8192, kt = e >> 6, fl = e & 63;
    const int r0 = kt * 32 + ((fl >> 4) << 3);
    const int c  = fl & 15;
    float aw[8];
#pragma unroll
    for (int j = 0; j < 8; ++j) aw[j] = 0.f;
    for (int m = 0; m < SDIM; ++m) {
      const float bm = Bmat[m * CDIM + c];
#pragma unroll
      for (int j = 0; j < 8; ++j) aw[j] = fmaf(W3[(r0 + j) * SDIM + m], bm, aw[j]);
    }
    f16x8 v;
#pragma unroll
    for (int j = 0; j < 8; ++j) v[j] = (f16)aw[j];
    *(f16x8*)((f16*)(ws + OFF_W3P) + (size_t)e * 8) = v;
  } else if (gid < 10752) {
    const int e = gid - 8704;
    const int lane = e & 63, tt = e >> 6;
    const int nt = tt & 15, kt = tt >> 4;
    const int m = nt * 16 + (lane & 15);
    const int k0 = kt * 32 + ((lane >> 4) << 3);
    f16x8 v;
#pragma unroll
    for (int j = 0; j < 8; ++j) v[j] = (f16)W1[(k0 + j) * HID + m];
    *(f16x8*)((f16*)(ws + OFF_W1P) + (size_t)e * 8) = v;
  } else if (gid < 11008) {
    const int h = gid - 10752;
    ((float*)(ws + OFF_B1E))[h] = b1[h] + t[0] * W1[SDIM * HID + h];  // fold t-col
  } else if (gid < 11024) {
    const int c = gid - 11008;
    float s = 0.f;
    for (int m = 0; m < SDIM; ++m) s = fmaf(b3[m], Bmat[m * CDIM + c], s);
    ((float*)(ws + OFF_B3B))[c] = s;
  }
}

// ---- main: 256 blocks x 512 threads (8 waves), 144 KB LDS, 1 block/CU ----
__global__ __launch_bounds__(512, 2)
void oc_main(const float* __restrict__ x, const float* __restrict__ b2,
             const char* __restrict__ ws, float* __restrict__ out) {
  __shared__ f16 sH1[BM * 256];   // H1 [batch][hidden] swizzled
  __shared__ f16 sH2[BM * 256];   // H2 (single fp16 -- no lo residual)
  __shared__ f16 sX [BM * 64];    // staged X [batch][k] swizzled
  const int tid  = threadIdx.x;
  const int wave = tid >> 6, lane = tid & 63;
  const int q    = lane >> 4, l = lane & 15;

  const f16* W2p = (const f16*)(ws + OFF_W2P);
  const f16* W3p = (const f16*)(ws + OFF_W3P);
  const f16* W1p = (const f16*)(ws + OFF_W1P);

  // ---- initial X stage: 2048 float4, 4 per thread ----
  {
    const float* xp = x + (size_t)blockIdx.x * BM * SDIM;
#pragma unroll
    for (int i = 0; i < 4; ++i) {
      const int e = i * 512 + tid;           // 2048 float4 = 128 x 64 floats
      const int r = e >> 4, k4 = (e & 15) * 4;
      const float4 v = *(const float4*)(xp + r * SDIM + k4);
      f16x4 w = {(f16)v.x, (f16)v.y, (f16)v.z, (f16)v.w};
      *(f16x4*)(&sX[sx_idx(r, k4)]) = w;
    }
  }

  // ---- biases: wave owns 32 hidden (mt 0..1), h0 = 32*wave + 16*mt + 4*q ----
  f32x4 b1e[2], b2e[2];
#pragma unroll
  for (int mt = 0; mt < 2; ++mt) {
    const int h0 = 32 * wave + 16 * mt + 4 * q;
    const float4 v1 = *(const float4*)((const float*)(ws + OFF_B1E) + h0);
    const float4 v2 = *(const float4*)(b2 + h0);
    b1e[mt] = (f32x4){v1.x, v1.y, v1.z, v1.w};
    b2e[mt] = (f32x4){v2.x, v2.y, v2.z, v2.w};
  }
  f32x4 b3t;
  {
    const float4 v = *(const float4*)((const float*)(ws + OFF_B3B) + 4 * q);
    b3t = (f32x4){v.x, v.y, v.z, v.w};
  }
  __syncthreads();   // sX staged (acts as barrier D for it=-1)

  f32x4 acc[2][8];   // [mt][nt]

  for (int it = 0; it < ITERS; ++it) {
    const int tile = blockIdx.x + it * GRID;

    // ---- P0 / layer 1: H1 = relu(W1^T X^T + b1); M=32/wave, N=128 batch ----
#pragma unroll
    for (int mt = 0; mt < 2; ++mt)
#pragma unroll
      for (int nt = 0; nt < 8; ++nt) acc[mt][nt] = b1e[mt];
#pragma unroll
    for (int kt = 0; kt < 2; ++kt) {
      const f16x8 w1a = *(const f16x8*)(W1p + ((size_t)(kt * 16 + 2 * wave    ) * 64 + lane) * 8);
      const f16x8 w1b = *(const f16x8*)(W1p + ((size_t)(kt * 16 + 2 * wave + 1) * 64 + lane) * 8);
#pragma unroll
      for (int nt = 0; nt < 8; ++nt) {
        const f16x8 b = *(const f16x8*)(&sX[sx_idx(16 * nt + l, 32 * kt + 8 * q)]);
        acc[0][nt] = MFMA(w1a, b, acc[0][nt]);
        acc[1][nt] = MFMA(w1b, b, acc[1][nt]);
      }
    }
#pragma unroll
    for (int mt = 0; mt < 2; ++mt) {
      const int h0 = 32 * wave + 16 * mt + 4 * q;
#pragma unroll
      for (int nt = 0; nt < 8; ++nt) {
        f16x4 v;
#pragma unroll
        for (int r = 0; r < 4; ++r) v[r] = (f16)fmaxf(acc[mt][nt][r], 0.f);
        *(f16x4*)(&sH1[sh_idx(16 * nt + l, h0)]) = v;
      }
    }
    __syncthreads();   // A: H1 visible; sX reads done

    // ---- P1 / layer 2: H2 = relu(W2^T H1 + b2), K=256; then writeback ----
#pragma unroll
    for (int mt = 0; mt < 2; ++mt)
#pragma unroll
      for (int nt = 0; nt < 8; ++nt) acc[mt][nt] = b2e[mt];
#pragma unroll
    for (int kt = 0; kt < 8; ++kt) {
      const f16x8 w2a = *(const f16x8*)(W2p + ((size_t)(kt * 16 + 2 * wave    ) * 64 + lane) * 8);
      const f16x8 w2b = *(const f16x8*)(W2p + ((size_t)(kt * 16 + 2 * wave + 1) * 64 + lane) * 8);
#pragma unroll
      for (int nt = 0; nt < 8; ++nt) {
        const f16x8 b = *(const f16x8*)(&sH1[sh_idx(16 * nt + l, 32 * kt + 8 * q)]);
        acc[0][nt] = MFMA(w2a, b, acc[0][nt]);
        acc[1][nt] = MFMA(w2b, b, acc[1][nt]);
      }
    }
    // H2 writeback: single fp16 store to sH2 (sH1 untouched -> no barrier B)
#pragma unroll
    for (int mt = 0; mt < 2; ++mt) {
      const int h0 = 32 * wave + 16 * mt + 4 * q;
#pragma unroll
      for (int nt = 0; nt < 8; ++nt) {
        f16x4 hi;
#pragma unroll
        for (int r = 0; r < 4; ++r) hi[r] = (f16)fmaxf(acc[mt][nt][r], 0.f);
        *(f16x4*)(&sH2[sh_idx(16 * nt + l, h0)]) = hi;
      }
    }
    __syncthreads();   // C: H2 visible

    // ---- P2: layer 3 (waves 0-3) || stage next X (waves 4-7) ----
    if (wave < 4) {
#pragma unroll
      for (int g = 0; g < 2; ++g) {
        const int row = 32 * wave + 16 * g + l;
        f32x4 a3 = b3t;
#pragma unroll
        for (int kt = 0; kt < 8; ++kt) {
          const f16x8 w3 = *(const f16x8*)(W3p + ((size_t)kt * 64 + lane) * 8);
          const f16x8 bh = *(const f16x8*)(&sH2[sh_idx(row, 32 * kt + 8 * q)]);
          a3 = MFMA(w3, bh, a3);
        }
        f32x4 o;
#pragma unroll
        for (int r = 0; r < 4; ++r)
          o[r] = fminf(fmaxf(-a3[r], -1.f), 1.f);
        *(float4*)(&out[((size_t)tile * BM + row) * CDIM + 4 * q]) = *(float4*)&o;
      }
    } else if (it + 1 < ITERS) {
      const float* xp = x + (size_t)(tile + GRID) * BM * SDIM;
      const int tid2 = tid - 256;            // 0..255
#pragma unroll
      for (int i = 0; i < 8; ++i) {
        const int e = i * 256 + tid2;        // 2048 float4 = 128 x 64 floats
        const int r = e >> 4, k4 = (e & 15) * 4;
        const float4 v = *(const float4*)(xp + r * SDIM + k4);
        f16x4 w = {(f16)v.x, (f16)v.y, (f16)v.z, (f16)v.w};
        *(f16x4*)(&sX[sx_idx(r, k4)]) = w;
      }
    }
    __syncthreads();   // D: L3 sH2 reads + sX stage done before next tile
  }
}

extern "C" void kernel_launch(void* const* d_in, const int* in_sizes, int n_in,
                              void* d_out, int out_size, void* d_ws, size_t ws_size,
                              hipStream_t stream) {
  const float* x    = (const float*)d_in[0];
  const float* t    = (const float*)d_in[1];
  const float* W1   = (const float*)d_in[2];
  const float* b1   = (const float*)d_in[3];
  const float* W2   = (const float*)d_in[4];
  const float* b2   = (const float*)d_in[5];
  const float* W3   = (const float*)d_in[6];
  const float* b3   = (const float*)d_in[7];
  const float* Bmat = (const float*)d_in[8];
  float* out = (float*)d_out;
  char*  ws  = (char*)d_ws;

  hipLaunchKernelGGL(oc_pack, dim3(22), dim3(512), 0, stream,
                     t, W1, b1, W2, W3, b3, Bmat, ws);
  hipLaunchKernelGGL(oc_main, dim3(GRID), dim3(512), 0, stream,
                     x, b2, ws, out);
}